// Round 7
// baseline (575.366 us; speedup 1.0000x reference)
//
#include <hip/hip_runtime.h>

// B=4, T=2048, D_MODEL=2048, H=16, KV=8, HD=128, G=2. f32 storage in/out,
// bf16 MFMA internals, fp32 accum. Compare threshold is bf16-lenient.

typedef unsigned short u16;
typedef unsigned int u32;
typedef __attribute__((ext_vector_type(8))) short bf16x8;
typedef __attribute__((ext_vector_type(4))) float f32x4;

__device__ __forceinline__ float bf2f(u16 v) {
    union { u32 u; float f; } x; x.u = ((u32)v) << 16; return x.f;
}
__device__ __forceinline__ u16 f2bf(float f) {
    union { float f; u32 u; } x; x.f = f;
    u32 u = x.u;
    return (u16)((u + 0x7FFFu + ((u >> 16) & 1u)) >> 16);  // RNE
}
// truncating pack of two f32 -> two bf16 (p >= 0, hot loop only)
__device__ __forceinline__ u32 packtrunc(float a, float b) {
    union { float f; u32 u; } x, y; x.f = a; y.f = b;
    return (x.u >> 16) | (y.u & 0xffff0000u);
}
__device__ __forceinline__ f32x4 mfma_bf16(bf16x8 a, bf16x8 b, f32x4 c) {
    return __builtin_amdgcn_mfma_f32_16x16x32_bf16(a, b, c, 0, 0, 0);
}
// async global->LDS, 16B/lane; LDS dest = wave-uniform base + lane*16
__device__ __forceinline__ void gl_lds16(const u16* g, u16* l) {
    __builtin_amdgcn_global_load_lds((const __attribute__((address_space(1))) void*)g,
                                     (__attribute__((address_space(3))) void*)l, 16, 0, 0);
}

// ---------------------------------------------------------------------------
// Transpose + cast f32 -> bf16: in[R][C] f32 -> out[C][R] bf16.
// ---------------------------------------------------------------------------
__global__ __launch_bounds__(256)
void transpose_f2b(const float* __restrict__ in, u16* __restrict__ out, int R, int C) {
    __shared__ float tile[32][33];
    const int tx = threadIdx.x & 31, ty = threadIdx.x >> 5;
    const long c0 = (long)blockIdx.x * 32, r0 = (long)blockIdx.y * 32;
#pragma unroll
    for (int i = 0; i < 4; i++)
        tile[ty + i * 8][tx] = in[(r0 + ty + i * 8) * C + c0 + tx];
    __syncthreads();
#pragma unroll
    for (int i = 0; i < 4; i++)
        out[(c0 + ty + i * 8) * R + r0 + tx] = f2bf(tile[tx][ty + i * 8]);
}

// ---------------------------------------------------------------------------
// Straight cast f32 -> bf16, 8 elem/thread.
// ---------------------------------------------------------------------------
__global__ __launch_bounds__(256)
void cast_f2b(const float* __restrict__ in, u16* __restrict__ out) {
    const long i = ((long)blockIdx.x * 256 + threadIdx.x) * 8;
    float4 a = *(const float4*)(in + i);
    float4 b = *(const float4*)(in + i + 4);
    bf16x8 v;
    v[0] = (short)f2bf(a.x); v[1] = (short)f2bf(a.y);
    v[2] = (short)f2bf(a.z); v[3] = (short)f2bf(a.w);
    v[4] = (short)f2bf(b.x); v[5] = (short)f2bf(b.y);
    v[6] = (short)f2bf(b.z); v[7] = (short)f2bf(b.w);
    *(bf16x8*)(out + i) = v;
}

// ---------------------------------------------------------------------------
// bf16 transpose of the V slice of qkv: qkv[token][3072 + d'] -> Vt[b][d'][t]
// ---------------------------------------------------------------------------
__global__ __launch_bounds__(256)
void transpose_v(const u16* __restrict__ qkv, u16* __restrict__ Vt) {
    __shared__ u16 tile[32][33];
    const int tx = threadIdx.x & 31, ty = threadIdx.x >> 5;
    const int d0 = blockIdx.x * 32;
    const int tok0 = blockIdx.y * 32;
#pragma unroll
    for (int i = 0; i < 4; i++)
        tile[ty + i * 8][tx] = qkv[(long)(tok0 + ty + i * 8) * 4096 + 3072 + d0 + tx];
    __syncthreads();
    const int b = tok0 >> 11;
    const long orow = (long)b * 1024 + d0;
    const int t0 = tok0 & 2047;
#pragma unroll
    for (int i = 0; i < 4; i++)
        Vt[(orow + ty + i * 8) * 2048 + t0 + tx] = tile[tx][ty + i * 8];
}

// ---------------------------------------------------------------------------
// GEMM v4 (256^2-tile, 8-wave, m201-style 4-phase/K-tile counted-vmcnt):
//   C[M][N] = A[M][K] @ Bt[N][K]^T, bf16 in, fp32 accum.
// BM=BN=256, BK=64. 512 threads = 8 waves (2M x 4N), wave owns 128x64.
// LDS 128 KiB as half-tile rings As/Bs[2 parity][2 half][128*64]; 16B-chunk
// XOR swizzle, staged via global_load_lds with pre-swizzled global source.
// Per K-tile t (parity par=t&1), 4 phases (kk = ph>>1, mh = ph&1):
//   ph0: stage A0,B0 of t+1 -> s_waitcnt vmcnt(4) [t's 8 done, 4 in flight]
//        -> barrier -> ds_read (4 af + 4 bv) -> lgkm(0) -> setprio+16 MFMA
//        -> barrier
//   ph1: ds_read 4 af; stage A1,B1 of t+1; barrier; lgkm(0); MFMA; barrier
//   ph2: ds_read 4 af + 4 bv (kk=1); barrier; lgkm(0); MFMA; barrier
//   ph3: ds_read 4 af; barrier; lgkm(0); MFMA; barrier
// vmcnt never drains to 0 in the main loop (T4); setprio around each MFMA
// cluster (T5). Hazards: stage targets parity par^1 whose last reads
// completed before tile t-1's final lgkm+barrier; ph0's vmcnt+barrier
// validates tile t globally before any ds_read of it.
// ---------------------------------------------------------------------------
template <bool F32OUT>
__global__ __launch_bounds__(512, 2)
void gemm_bt_256(const u16* __restrict__ A, const u16* __restrict__ Bt,
                 void* __restrict__ Cp, int M, int N, int K) {
    __shared__ __align__(16) u16 As[2][2][128 * 64];   // 64 KB
    __shared__ __align__(16) u16 Bs[2][2][128 * 64];   // 64 KB
    const int tid = threadIdx.x, wid = tid >> 6, lane = tid & 63;
    const int q4 = lane >> 4, n16 = lane & 15;
    const int wr = (wid >> 2) * 128;      // wave row offset in tile
    const int wc = (wid & 3) * 64;        // wave col offset in tile
    const int Ah = wr >> 7;               // wave's A half (0/1)
    const int Bh = wc >> 7;               // wave's B half (0/1)
    const int brow0 = wc & 64;            // B row base within its half

    // XCD-aware tile swizzle (nwg % 8 == 0 for all our shapes)
    const int nbx = N >> 8;
    const int nwg = nbx * (M >> 8);
    int id = (int)blockIdx.x;
    id = (id & 7) * (nwg >> 3) + (id >> 3);
    const long rowT = (long)(id / nbx) * 256;
    const long colT = (long)(id % nbx) * 256;

    // staging map: half h, load l covers rows h*128 + l*64 + (tid>>3);
    // lane's 16B chunk slot = tid&7 (linear in LDS), global g = slot^(row&7).
    const int srow = tid >> 3;                     // 0..63
    const int gchunk = (tid & 7) ^ (srow & 7);
    const u16* Ag[2][2]; const u16* Bg[2][2];
#pragma unroll
    for (int h = 0; h < 2; h++)
#pragma unroll
        for (int l = 0; l < 2; l++) {
            Ag[h][l] = A  + (rowT + h * 128 + l * 64 + srow) * K + gchunk * 8;
            Bg[h][l] = Bt + (colT + h * 128 + l * 64 + srow) * K + gchunk * 8;
        }
    const int ldst = wid * 512 + lane * 8;         // u16 offset within a half

    auto stageA = [&](int par, int h, int kt) {
#pragma unroll
        for (int l = 0; l < 2; l++)
            gl_lds16(Ag[h][l] + kt, &As[par][h][l * 4096 + ldst]);
    };
    auto stageB = [&](int par, int h, int kt) {
#pragma unroll
        for (int l = 0; l < 2; l++)
            gl_lds16(Bg[h][l] + kt, &Bs[par][h][l * 4096 + ldst]);
    };

    f32x4 acc[8][4];
#pragma unroll
    for (int i = 0; i < 8; i++)
#pragma unroll
        for (int j = 0; j < 4; j++) acc[i][j] = (f32x4){0.f, 0.f, 0.f, 0.f};

    const int fs = n16 & 7;    // frag row & 7 (all row bases are multiples of 8)

    // prologue: tile 0 fully staged (8 loads in flight)
    stageA(0, 0, 0); stageB(0, 0, 0); stageA(0, 1, 0); stageB(0, 1, 0);

    const int NT = K >> 6;
    for (int t = 0; t < NT; ++t) {
        const int par = t & 1, nxt = par ^ 1;
        const int ktn = (t + 1) << 6;
        const bool more = (t + 1 < NT);
        const u16* Acur = As[par][Ah];
        const u16* Bcur = Bs[par][Bh];
        bf16x8 bv[4];
#pragma unroll
        for (int ph = 0; ph < 4; ph++) {
            const int kk = ph >> 1, mh = ph & 1;
            if (ph == 0) {
                if (more) {
                    stageA(nxt, 0, ktn); stageB(nxt, 0, ktn);
                    asm volatile("s_waitcnt vmcnt(4)" ::: "memory");
                } else {
                    asm volatile("s_waitcnt vmcnt(0)" ::: "memory");
                }
                __builtin_amdgcn_sched_barrier(0);
                __builtin_amdgcn_s_barrier();
            }
            // ds_read this phase's fragments
            bf16x8 af[4];
            const int slot = ((kk * 4 + q4) ^ fs) * 8;
#pragma unroll
            for (int mb = 0; mb < 4; mb++)
                af[mb] = *(const bf16x8*)&Acur[((mh * 4 + mb) * 16 + n16) * 64 + slot];
            if (mh == 0) {
#pragma unroll
                for (int nb = 0; nb < 4; nb++)
                    bv[nb] = *(const bf16x8*)&Bcur[(brow0 + nb * 16 + n16) * 64 + slot];
            }
            if (ph == 1 && more) { stageA(nxt, 1, ktn); stageB(nxt, 1, ktn); }
            if (ph != 0) __builtin_amdgcn_s_barrier();
            asm volatile("s_waitcnt lgkmcnt(0)" ::: "memory");
            __builtin_amdgcn_sched_barrier(0);
            __builtin_amdgcn_s_setprio(1);
#pragma unroll
            for (int mb = 0; mb < 4; mb++)
#pragma unroll
                for (int nb = 0; nb < 4; nb++)
                    acc[mh * 4 + mb][nb] = mfma_bf16(af[mb], bv[nb], acc[mh * 4 + mb][nb]);
            __builtin_amdgcn_s_setprio(0);
            __builtin_amdgcn_s_barrier();
        }
    }

#pragma unroll
    for (int mb = 0; mb < 8; mb++)
#pragma unroll
        for (int nb = 0; nb < 4; nb++)
#pragma unroll
            for (int r = 0; r < 4; r++) {
                long row = rowT + wr + mb * 16 + q4 * 4 + r;
                long col = colT + wc + nb * 16 + n16;
                if (F32OUT) ((float*)Cp)[row * N + col] = acc[mb][nb][r];
                else        ((u16*)Cp)[row * N + col]   = f2bf(acc[mb][nb][r]);
            }
}

// ---------------------------------------------------------------------------
// RMSNorm + interleaved RoPE in-place on bf16 qkv [8192][4096].
// q-heads scaled by (1/sqrt(128))*log2(e): folds softmax scale + exp2 domain.
// ---------------------------------------------------------------------------
__global__ __launch_bounds__(256)
void rmsnorm_rope(u16* __restrict__ qkv, const float* __restrict__ cosT,
                  const float* __restrict__ sinT, const float* __restrict__ qg,
                  const float* __restrict__ kg) {
    const int w = blockIdx.x * 4 + (threadIdx.x >> 6);
    const int lane = threadIdx.x & 63;
    const int token = w / 24;
    const int hv = w - token * 24;
    const long base = (long)token * 4096 + (hv < 16 ? hv * 128 : 2048 + (hv - 16) * 128);
    const float* g = (hv < 16) ? qg : kg;
    const int t = token & 2047;

    u32 pair = *(const u32*)(qkv + base + 2 * lane);
    float a0 = bf2f((u16)(pair & 0xffffu));
    float a1 = bf2f((u16)(pair >> 16));
    float ss = a0 * a0 + a1 * a1;
#pragma unroll
    for (int off = 32; off > 0; off >>= 1) ss += __shfl_xor(ss, off);
    float rs = rsqrtf(ss * (1.0f / 128.0f) + 1e-6f);
    float h0 = a0 * rs * g[2 * lane];
    float h1 = a1 * rs * g[2 * lane + 1];
    float2 cp = *(const float2*)(cosT + (long)t * 128 + 2 * lane);
    float2 sp = *(const float2*)(sinT + (long)t * 128 + 2 * lane);
    float o0 = h0 * cp.x - h1 * sp.x;
    float o1 = h1 * cp.y + h0 * sp.y;
    if (hv < 16) {
        const float QS = 0.08838834764831845f * 1.4426950408889634f;
        o0 *= QS; o1 *= QS;
    }
    *(u32*)(qkv + base + 2 * lane) = ((u32)f2bf(o0)) | (((u32)f2bf(o1)) << 16);
}

// ---------------------------------------------------------------------------
// Flash attention v6: v4 structure (KVBLK=64, 64 KB LDS, 2 blocks/CU) +
// VALU diet + XCD-affinity grid remap.
//   - raw exp2 (no SHIFT): s <= 16.33 -> p <= 8.4e4, bf16-safe; O/l
//     cancels all scaling.
//   - l via MFMA with all-ones B-frag: l_acc C-layout == o layout ->
//     epilogue divides with ZERO shuffles.
//   - grid remap: linear bid -> (xq, hy) with bid === hy (mod 8), so all
//     16 Q-blocks of one (b,h) land on ONE XCD consecutively -> K/V slice
//     (1 MB) is fetched into one L2 and reused 16x (FETCH 147->49 MB, r6).
// K rows staged in permuted token order t(rho) = (rho&32)|((rho&12)<<1)|
// ((rho&16)>>2)|(rho&3): the QK^T C-fragment each lane holds IS its PV
// A-fragment (P never touches LDS). Both-sides XOR chunk swizzle on K/V.
// Grid 1024: xq = 128-row Q tile (16), hy = b*16+h (64); 4 waves.
// ---------------------------------------------------------------------------
__global__ __launch_bounds__(256)
void flash_attn(const u16* __restrict__ qkv, const u16* __restrict__ Vt,
                u16* __restrict__ attn) {
    __shared__ __align__(16) u16 Ks[2][64 * 128];    // 32 KB
    __shared__ __align__(16) u16 Vs[2][128 * 64];    // 32 KB
    const int tid = threadIdx.x, wid = tid >> 6, lane = tid & 63;
    const int q4 = lane >> 4, n16 = lane & 15;

    // XCD-affinity remap (bijective on 0..1023): bid%8 picks the XCD slot,
    // consecutive bids on one XCD walk all 16 xq of one hy before moving on.
    const int bid = (int)(blockIdx.x + (blockIdx.y << 4));
    const int xq  = (bid >> 3) & 15;
    const int hy  = ((bid >> 7) << 3) | (bid & 7);
    const int b = hy >> 4, h = hy & 15;
    const int kvh = h >> 1;
    const long rowbase = (long)b * 2048;
    const long qbase = rowbase + (long)xq * 128 + wid * 32;

    const u16* Kbase = qkv + rowbase * 4096 + 2048 + kvh * 128;     // + t*4096 + d
    const u16* Vbase = Vt + ((long)(b * 8 + kvh) * 128) * 2048;     // + d*2048 + t

    // staging maps (per wave, 4 instrs each for K and V)
    // K instr i: LDS row rho = wid*16 + i*4 + (lane>>4), slot = lane&15,
    //            global token = t(rho) [permuted], chunk g = slot ^ (rho&7)
    const int krow_off = lane >> 4;                   // 0..3
    const int kslot = lane & 15;
    int ktr[4], kgc[4];
#pragma unroll
    for (int i = 0; i < 4; i++) {
        int rho = wid * 16 + i * 4 + krow_off;
        ktr[i] = (rho & 32) | ((rho & 12) << 1) | ((rho & 16) >> 2) | (rho & 3);
        kgc[i] = kslot ^ (rho & 7);
    }
    // V instr i: row d = wid*32 + i*8 + (lane>>3), slot = lane&7, g = slot^(d&7)
    const int vrow_off = lane >> 3;                   // 0..7
    const int vslot = lane & 7;
    const int vg = vslot ^ vrow_off;                  // d&7 == lane>>3 here

    auto stage = [&](int buf, int kt) {
#pragma unroll
        for (int i = 0; i < 4; i++)
            gl_lds16(Kbase + (long)(kt + ktr[i]) * 4096 + kgc[i] * 8,
                     &Ks[buf][(wid * 16 + i * 4) * 128 + lane * 8]);
#pragma unroll
        for (int i = 0; i < 4; i++) {
            int d = wid * 32 + i * 8 + vrow_off;
            gl_lds16(Vbase + (long)d * 2048 + kt + vg * 8,
                     &Vs[buf][(wid * 32 + i * 8) * 64 + lane * 8]);
        }
    };

    // Q B-frags (resident; once per block, gather is amortized)
    bf16x8 qf[2][4];
#pragma unroll
    for (int qb = 0; qb < 2; qb++) {
        const u16* p = qkv + (qbase + qb * 16 + n16) * 4096 + h * 128;
#pragma unroll
        for (int c = 0; c < 4; c++) qf[qb][c] = *(const bf16x8*)(p + c * 32 + q4 * 8);
    }

    f32x4 o[2][8];
#pragma unroll
    for (int i = 0; i < 2; i++)
#pragma unroll
        for (int j = 0; j < 8; j++) o[i][j] = (f32x4){0.f, 0.f, 0.f, 0.f};
    f32x4 l_acc[2] = {(f32x4){0.f, 0.f, 0.f, 0.f}, (f32x4){0.f, 0.f, 0.f, 0.f}};

    bf16x8 ones;
#pragma unroll
    for (int j = 0; j < 8; j++) ones[j] = (short)0x3f80;   // bf16 1.0

    const int swz = n16 & 7;              // fragment-read swizzle key

    // prologue: fill buffer 0 and drain
    stage(0, 0);
    asm volatile("s_waitcnt vmcnt(0)" ::: "memory");
    __builtin_amdgcn_s_barrier();

    int cur = 0;
    for (int kt = 0; kt < 2048; kt += 64) {
        // ---- issue next tile's staging into the other buffer (async) ----
        if (kt + 64 < 2048) stage(cur ^ 1, kt + 64);

        const u16* KsC = Ks[cur];
        const u16* VsC = Vs[cur];

        // ---- S^T = K Q^T from LDS (rows are token-permuted) ----
        f32x4 s[2][4];
#pragma unroll
        for (int qb = 0; qb < 2; qb++)
#pragma unroll
            for (int kb = 0; kb < 4; kb++) s[qb][kb] = (f32x4){0.f, 0.f, 0.f, 0.f};
#pragma unroll
        for (int c = 0; c < 4; c++) {
            bf16x8 kf[4];
#pragma unroll
            for (int kb = 0; kb < 4; kb++) {
                int slot = (c * 4 + q4) ^ swz;
                kf[kb] = *(const bf16x8*)&KsC[(kb * 16 + n16) * 128 + slot * 8];
            }
            __builtin_amdgcn_s_setprio(1);
#pragma unroll
            for (int qb = 0; qb < 2; qb++)
#pragma unroll
                for (int kb = 0; kb < 4; kb++)
                    s[qb][kb] = mfma_bf16(kf[kb], qf[qb][c], s[qb][kb]);
            __builtin_amdgcn_s_setprio(0);
        }

        // ---- raw exp2 (no shift); pack P in registers.
        //      s[qb][kb][r] = score of token kc*32 + q4*8 + (kb&1)*4 + r
        //      (kc = kb>>1) -- exactly the PV A-fragment slot order.
        u32 pw[2][8];
#pragma unroll
        for (int qb = 0; qb < 2; qb++)
#pragma unroll
            for (int kb = 0; kb < 4; kb++) {
                float p0 = exp2f(s[qb][kb][0]);
                float p1 = exp2f(s[qb][kb][1]);
                float p2 = exp2f(s[qb][kb][2]);
                float p3 = exp2f(s[qb][kb][3]);
                pw[qb][kb * 2]     = packtrunc(p0, p1);
                pw[qb][kb * 2 + 1] = packtrunc(p2, p3);
            }

        // ---- PV + l: A = P (registers), B = V^T-frag / ones const ----
#pragma unroll
        for (int kc = 0; kc < 2; kc++) {
            bf16x8 vf[8];
#pragma unroll
            for (int nbh = 0; nbh < 8; nbh++) {
                int slot = (kc * 4 + q4) ^ swz;
                vf[nbh] = *(const bf16x8*)&VsC[(nbh * 16 + n16) * 64 + slot * 8];
            }
            __builtin_amdgcn_s_setprio(1);
#pragma unroll
            for (int qb = 0; qb < 2; qb++) {
                union { u32 w[4]; bf16x8 v; } pu;
                pu.w[0] = pw[qb][kc * 4];
                pu.w[1] = pw[qb][kc * 4 + 1];
                pu.w[2] = pw[qb][kc * 4 + 2];
                pu.w[3] = pw[qb][kc * 4 + 3];
                l_acc[qb] = mfma_bf16(pu.v, ones, l_acc[qb]);
#pragma unroll
                for (int nbh = 0; nbh < 8; nbh++)
                    o[qb][nbh] = mfma_bf16(pu.v, vf[nbh], o[qb][nbh]);
            }
            __builtin_amdgcn_s_setprio(0);
        }

        // ---- next buffer landed + all waves done reading cur ----
        asm volatile("s_waitcnt vmcnt(0)" ::: "memory");
        __builtin_amdgcn_s_barrier();
        cur ^= 1;
    }

    // ---- epilogue: O /= l (same-lane, same-reg layout), write bf16 ----
#pragma unroll
    for (int qb = 0; qb < 2; qb++) {
        float linv[4];
#pragma unroll
        for (int r = 0; r < 4; r++) linv[r] = 1.0f / l_acc[qb][r];
#pragma unroll
        for (int r = 0; r < 4; r++) {
            u16* op = attn + (qbase + qb * 16 + q4 * 4 + r) * 2048 + h * 128 + n16;
#pragma unroll
            for (int nbh = 0; nbh < 8; nbh++)
                op[nbh * 16] = f2bf(o[qb][nbh][r] * linv[r]);
        }
    }
}

// ---------------------------------------------------------------------------
// ws layout (bytes), total 125.8 MB:
//   Bt_qkv / Vt  @ 0          16,777,216   (Vt overwrites Bt_qkv after gemm_qkv)
//   Bt_o         @ 16777216    8,388,608
//   xb / attn    @ 25165824   33,554,432   (attn overwrites xb after gemm_qkv)
//   qkv          @ 58720256   67,108,864
// ---------------------------------------------------------------------------
extern "C" void kernel_launch(void* const* d_in, const int* in_sizes, int n_in,
                              void* d_out, int out_size, void* d_ws, size_t ws_size,
                              hipStream_t stream) {
    const float* x    = (const float*)d_in[0];
    const float* cosT = (const float*)d_in[1];
    const float* sinT = (const float*)d_in[2];
    const float* Wq   = (const float*)d_in[3];
    const float* Wk   = (const float*)d_in[4];
    const float* Wv   = (const float*)d_in[5];
    const float* Wo   = (const float*)d_in[6];
    const float* qg   = (const float*)d_in[7];
    const float* kg   = (const float*)d_in[8];
    float* out = (float*)d_out;

    char* ws = (char*)d_ws;
    u16* Bt_qkv = (u16*)(ws);
    u16* Vt     = (u16*)(ws);              // reuses Bt_qkv after gemm_qkv
    u16* Bt_o   = (u16*)(ws + 16777216);
    u16* xb     = (u16*)(ws + 25165824);
    u16* attn   = (u16*)(ws + 25165824);   // reuses xb after gemm_qkv
    u16* qkv    = (u16*)(ws + 58720256);

    transpose_f2b<<<dim3(64, 64), 256, 0, stream>>>(Wq, Bt_qkv, 2048, 2048);
    transpose_f2b<<<dim3(32, 64), 256, 0, stream>>>(Wk, Bt_qkv + (size_t)2048 * 2048, 2048, 1024);
    transpose_f2b<<<dim3(32, 64), 256, 0, stream>>>(Wv, Bt_qkv + (size_t)3072 * 2048, 2048, 1024);
    transpose_f2b<<<dim3(64, 64), 256, 0, stream>>>(Wo, Bt_o, 2048, 2048);
    cast_f2b<<<dim3(8192), 256, 0, stream>>>(x, xb);

    gemm_bt_256<false><<<dim3(512), 512, 0, stream>>>(xb, Bt_qkv, qkv, 8192, 4096, 2048);

    transpose_v<<<dim3(32, 256), 256, 0, stream>>>(qkv, Vt);
    rmsnorm_rope<<<dim3(49152), 256, 0, stream>>>(qkv, cosT, sinT, qg, kg);

    flash_attn<<<dim3(16, 64), 256, 0, stream>>>(qkv, Vt, attn);

    gemm_bt_256<true><<<dim3(256), 512, 0, stream>>>(attn, Bt_o, out, 8192, 2048, 2048);
}

// Round 8
// 532.202 us; speedup vs baseline: 1.0811x; 1.0811x over previous
//
#include <hip/hip_runtime.h>

// B=4, T=2048, D_MODEL=2048, H=16, KV=8, HD=128, G=2. f32 storage in/out,
// bf16 MFMA internals, fp32 accum. Compare threshold is bf16-lenient.

typedef unsigned short u16;
typedef unsigned int u32;
typedef __attribute__((ext_vector_type(8))) short bf16x8;
typedef __attribute__((ext_vector_type(4))) float f32x4;

__device__ __forceinline__ float bf2f(u16 v) {
    union { u32 u; float f; } x; x.u = ((u32)v) << 16; return x.f;
}
__device__ __forceinline__ u16 f2bf(float f) {
    union { float f; u32 u; } x; x.f = f;
    u32 u = x.u;
    return (u16)((u + 0x7FFFu + ((u >> 16) & 1u)) >> 16);  // RNE
}
// truncating pack of two f32 -> two bf16 (p >= 0, hot loop only)
__device__ __forceinline__ u32 packtrunc(float a, float b) {
    union { float f; u32 u; } x, y; x.f = a; y.f = b;
    return (x.u >> 16) | (y.u & 0xffff0000u);
}
// raw v_exp_f32: D = 2^S0. Domain here is |x| <= 16.33 (RMSNorm bound), so
// OCML's overflow/denorm guard sequence (~8 VALU instrs) is dead weight.
__device__ __forceinline__ float fexp2(float x) {
    float r; asm("v_exp_f32 %0, %1" : "=v"(r) : "v"(x)); return r;
}
__device__ __forceinline__ f32x4 mfma_bf16(bf16x8 a, bf16x8 b, f32x4 c) {
    return __builtin_amdgcn_mfma_f32_16x16x32_bf16(a, b, c, 0, 0, 0);
}
// async global->LDS, 16B/lane; LDS dest = wave-uniform base + lane*16
__device__ __forceinline__ void gl_lds16(const u16* g, u16* l) {
    __builtin_amdgcn_global_load_lds((const __attribute__((address_space(1))) void*)g,
                                     (__attribute__((address_space(3))) void*)l, 16, 0, 0);
}

// ---------------------------------------------------------------------------
// Transpose + cast f32 -> bf16: in[R][C] f32 -> out[C][R] bf16.
// ---------------------------------------------------------------------------
__global__ __launch_bounds__(256)
void transpose_f2b(const float* __restrict__ in, u16* __restrict__ out, int R, int C) {
    __shared__ float tile[32][33];
    const int tx = threadIdx.x & 31, ty = threadIdx.x >> 5;
    const long c0 = (long)blockIdx.x * 32, r0 = (long)blockIdx.y * 32;
#pragma unroll
    for (int i = 0; i < 4; i++)
        tile[ty + i * 8][tx] = in[(r0 + ty + i * 8) * C + c0 + tx];
    __syncthreads();
#pragma unroll
    for (int i = 0; i < 4; i++)
        out[(c0 + ty + i * 8) * R + r0 + tx] = f2bf(tile[tx][ty + i * 8]);
}

// ---------------------------------------------------------------------------
// Straight cast f32 -> bf16, 8 elem/thread.
// ---------------------------------------------------------------------------
__global__ __launch_bounds__(256)
void cast_f2b(const float* __restrict__ in, u16* __restrict__ out) {
    const long i = ((long)blockIdx.x * 256 + threadIdx.x) * 8;
    float4 a = *(const float4*)(in + i);
    float4 b = *(const float4*)(in + i + 4);
    bf16x8 v;
    v[0] = (short)f2bf(a.x); v[1] = (short)f2bf(a.y);
    v[2] = (short)f2bf(a.z); v[3] = (short)f2bf(a.w);
    v[4] = (short)f2bf(b.x); v[5] = (short)f2bf(b.y);
    v[6] = (short)f2bf(b.z); v[7] = (short)f2bf(b.w);
    *(bf16x8*)(out + i) = v;
}

// ---------------------------------------------------------------------------
// bf16 transpose of the V slice of qkv: qkv[token][3072 + d'] -> Vt[b][d'][t]
// ---------------------------------------------------------------------------
__global__ __launch_bounds__(256)
void transpose_v(const u16* __restrict__ qkv, u16* __restrict__ Vt) {
    __shared__ u16 tile[32][33];
    const int tx = threadIdx.x & 31, ty = threadIdx.x >> 5;
    const int d0 = blockIdx.x * 32;
    const int tok0 = blockIdx.y * 32;
#pragma unroll
    for (int i = 0; i < 4; i++)
        tile[ty + i * 8][tx] = qkv[(long)(tok0 + ty + i * 8) * 4096 + 3072 + d0 + tx];
    __syncthreads();
    const int b = tok0 >> 11;
    const long orow = (long)b * 1024 + d0;
    const int t0 = tok0 & 2047;
#pragma unroll
    for (int i = 0; i < 4; i++)
        Vt[(orow + ty + i * 8) * 2048 + t0 + tx] = tile[tx][ty + i * 8];
}

// ---------------------------------------------------------------------------
// GEMM v3 (256^2-tile, 8-wave, T3 minimum-2-phase double buffer) — the
// round-6 proven config (4-phase port regressed, r7).
//   C[M][N] = A[M][K] @ Bt[N][K]^T, bf16 in, fp32 accum.
// BM=BN=256, BK=64. 512 threads = 8 waves (2M x 4N), wave owns 128x64.
// LDS 128 KiB: 2 full-tile buffers, 16B-chunk XOR swizzle; staged via
// global_load_lds with pre-swizzled global source. One barrier per tile,
// prefetch issued a full compute-phase before its drain.
// ---------------------------------------------------------------------------
template <bool F32OUT>
__global__ __launch_bounds__(512, 2)
void gemm_bt_256(const u16* __restrict__ A, const u16* __restrict__ Bt,
                 void* __restrict__ Cp, int M, int N, int K) {
    __shared__ __align__(16) u16 As[2][256 * 64];   // 64 KB
    __shared__ __align__(16) u16 Bs[2][256 * 64];   // 64 KB
    const int tid = threadIdx.x, wid = tid >> 6, lane = tid & 63;
    const int q4 = lane >> 4, n16 = lane & 15;
    const int wr = (wid >> 2) * 128;      // wave row offset in tile
    const int wc = (wid & 3) * 64;        // wave col offset in tile

    // XCD-aware tile swizzle (nwg % 8 == 0 for all our shapes)
    const int nbx = N >> 8;
    const int nwg = nbx * (M >> 8);
    int id = (int)blockIdx.x;
    id = (id & 7) * (nwg >> 3) + (id >> 3);
    const long rowT = (long)(id / nbx) * 256;
    const long colT = (long)(id % nbx) * 256;

    // staging map: instr i stages rows i*64 + (tid>>3); lane's 16B chunk slot
    // = tid&7 (linear in LDS), global chunk g = slot ^ (row&7).
    const int srow = tid >> 3;                     // 0..63
    const int gchunk = (tid & 7) ^ (srow & 7);
    const u16* Ag[4]; const u16* Bg[4];
#pragma unroll
    for (int i = 0; i < 4; i++) {
        Ag[i] = A  + (rowT + i * 64 + srow) * K + gchunk * 8;
        Bg[i] = Bt + (colT + i * 64 + srow) * K + gchunk * 8;
    }
    const int ldst = wid * 512 + lane * 8;         // u16 offset (wave base + lane*16B)

    auto stage = [&](int buf, int kt) {
#pragma unroll
        for (int i = 0; i < 4; i++)
            gl_lds16(Ag[i] + kt, &As[buf][i * 4096 + ldst]);
#pragma unroll
        for (int i = 0; i < 4; i++)
            gl_lds16(Bg[i] + kt, &Bs[buf][i * 4096 + ldst]);
    };

    f32x4 acc[8][4];
#pragma unroll
    for (int i = 0; i < 8; i++)
#pragma unroll
        for (int j = 0; j < 4; j++) acc[i][j] = (f32x4){0.f, 0.f, 0.f, 0.f};

    const int fs = n16 & 7;    // frag row & 7 (wr, wc, mb*16 are multiples of 8)

    // prologue: fill buffer 0 and drain
    stage(0, 0);
    asm volatile("s_waitcnt vmcnt(0)" ::: "memory");
    __builtin_amdgcn_s_barrier();

    const int NT = K >> 6;
    for (int t = 0; t < NT; ++t) {
        const int buf = t & 1;
        // ---- issue next tile's staging into the other buffer (async) ----
        if (t + 1 < NT) stage(buf ^ 1, (t + 1) << 6);

        const u16* Ac = As[buf];
        const u16* Bc = Bs[buf];
#pragma unroll
        for (int kk = 0; kk < 2; kk++) {
            const int slot = ((kk * 4 + q4) ^ fs) * 8;
            bf16x8 af[8], bv[4];
#pragma unroll
            for (int mb = 0; mb < 8; mb++)
                af[mb] = *(const bf16x8*)&Ac[(wr + mb * 16 + n16) * 64 + slot];
#pragma unroll
            for (int nb = 0; nb < 4; nb++)
                bv[nb] = *(const bf16x8*)&Bc[(wc + nb * 16 + n16) * 64 + slot];
#pragma unroll
            for (int mb = 0; mb < 8; mb++)
#pragma unroll
                for (int nb = 0; nb < 4; nb++)
                    acc[mb][nb] = mfma_bf16(af[mb], bv[nb], acc[mb][nb]);
        }
        // ---- next buffer landed + all waves done reading cur ----
        asm volatile("s_waitcnt vmcnt(0)" ::: "memory");
        __builtin_amdgcn_s_barrier();
    }

#pragma unroll
    for (int mb = 0; mb < 8; mb++)
#pragma unroll
        for (int nb = 0; nb < 4; nb++)
#pragma unroll
            for (int r = 0; r < 4; r++) {
                long row = rowT + wr + mb * 16 + q4 * 4 + r;
                long col = colT + wc + nb * 16 + n16;
                if (F32OUT) ((float*)Cp)[row * N + col] = acc[mb][nb][r];
                else        ((u16*)Cp)[row * N + col]   = f2bf(acc[mb][nb][r]);
            }
}

// ---------------------------------------------------------------------------
// RMSNorm + interleaved RoPE in-place on bf16 qkv [8192][4096].
// q-heads scaled by (1/sqrt(128))*log2(e): folds softmax scale + exp2 domain.
// ---------------------------------------------------------------------------
__global__ __launch_bounds__(256)
void rmsnorm_rope(u16* __restrict__ qkv, const float* __restrict__ cosT,
                  const float* __restrict__ sinT, const float* __restrict__ qg,
                  const float* __restrict__ kg) {
    const int w = blockIdx.x * 4 + (threadIdx.x >> 6);
    const int lane = threadIdx.x & 63;
    const int token = w / 24;
    const int hv = w - token * 24;
    const long base = (long)token * 4096 + (hv < 16 ? hv * 128 : 2048 + (hv - 16) * 128);
    const float* g = (hv < 16) ? qg : kg;
    const int t = token & 2047;

    u32 pair = *(const u32*)(qkv + base + 2 * lane);
    float a0 = bf2f((u16)(pair & 0xffffu));
    float a1 = bf2f((u16)(pair >> 16));
    float ss = a0 * a0 + a1 * a1;
#pragma unroll
    for (int off = 32; off > 0; off >>= 1) ss += __shfl_xor(ss, off);
    float rs = rsqrtf(ss * (1.0f / 128.0f) + 1e-6f);
    float h0 = a0 * rs * g[2 * lane];
    float h1 = a1 * rs * g[2 * lane + 1];
    float2 cp = *(const float2*)(cosT + (long)t * 128 + 2 * lane);
    float2 sp = *(const float2*)(sinT + (long)t * 128 + 2 * lane);
    float o0 = h0 * cp.x - h1 * sp.x;
    float o1 = h1 * cp.y + h0 * sp.y;
    if (hv < 16) {
        const float QS = 0.08838834764831845f * 1.4426950408889634f;
        o0 *= QS; o1 *= QS;
    }
    *(u32*)(qkv + base + 2 * lane) = ((u32)f2bf(o0)) | (((u32)f2bf(o1)) << 16);
}

// ---------------------------------------------------------------------------
// Flash attention v7: v6 structure (KVBLK=64, 64 KB LDS, 2 blocks/CU,
// VALU diet, XCD-affinity remap) + raw v_exp_f32 (fexp2) replacing the
// OCML exp2f guard sequence -- domain |s| <= 16.33 makes guards dead code.
//   - raw exp2 (no SHIFT): p <= 8.4e4, bf16-safe; O/l cancels scaling.
//   - l via MFMA with all-ones B-frag: l_acc C-layout == o layout ->
//     epilogue divides with ZERO shuffles.
//   - grid remap: all 16 Q-blocks of one (b,h) on ONE XCD consecutively ->
//     K/V slice fetched once per XCD (FETCH 147->49 MB, r6).
// K rows staged in permuted token order t(rho) = (rho&32)|((rho&12)<<1)|
// ((rho&16)>>2)|(rho&3): the QK^T C-fragment each lane holds IS its PV
// A-fragment (P never touches LDS). Both-sides XOR chunk swizzle on K/V.
// Grid 1024: xq = 128-row Q tile (16), hy = b*16+h (64); 4 waves.
// ---------------------------------------------------------------------------
__global__ __launch_bounds__(256)
void flash_attn(const u16* __restrict__ qkv, const u16* __restrict__ Vt,
                u16* __restrict__ attn) {
    __shared__ __align__(16) u16 Ks[2][64 * 128];    // 32 KB
    __shared__ __align__(16) u16 Vs[2][128 * 64];    // 32 KB
    const int tid = threadIdx.x, wid = tid >> 6, lane = tid & 63;
    const int q4 = lane >> 4, n16 = lane & 15;

    // XCD-affinity remap (bijective on 0..1023): bid%8 picks the XCD slot,
    // consecutive bids on one XCD walk all 16 xq of one hy before moving on.
    const int bid = (int)(blockIdx.x + (blockIdx.y << 4));
    const int xq  = (bid >> 3) & 15;
    const int hy  = ((bid >> 7) << 3) | (bid & 7);
    const int b = hy >> 4, h = hy & 15;
    const int kvh = h >> 1;
    const long rowbase = (long)b * 2048;
    const long qbase = rowbase + (long)xq * 128 + wid * 32;

    const u16* Kbase = qkv + rowbase * 4096 + 2048 + kvh * 128;     // + t*4096 + d
    const u16* Vbase = Vt + ((long)(b * 8 + kvh) * 128) * 2048;     // + d*2048 + t

    // staging maps (per wave, 4 instrs each for K and V)
    // K instr i: LDS row rho = wid*16 + i*4 + (lane>>4), slot = lane&15,
    //            global token = t(rho) [permuted], chunk g = slot ^ (rho&7)
    const int krow_off = lane >> 4;                   // 0..3
    const int kslot = lane & 15;
    int ktr[4], kgc[4];
#pragma unroll
    for (int i = 0; i < 4; i++) {
        int rho = wid * 16 + i * 4 + krow_off;
        ktr[i] = (rho & 32) | ((rho & 12) << 1) | ((rho & 16) >> 2) | (rho & 3);
        kgc[i] = kslot ^ (rho & 7);
    }
    // V instr i: row d = wid*32 + i*8 + (lane>>3), slot = lane&7, g = slot^(d&7)
    const int vrow_off = lane >> 3;                   // 0..7
    const int vslot = lane & 7;
    const int vg = vslot ^ vrow_off;                  // d&7 == lane>>3 here

    auto stage = [&](int buf, int kt) {
#pragma unroll
        for (int i = 0; i < 4; i++)
            gl_lds16(Kbase + (long)(kt + ktr[i]) * 4096 + kgc[i] * 8,
                     &Ks[buf][(wid * 16 + i * 4) * 128 + lane * 8]);
#pragma unroll
        for (int i = 0; i < 4; i++) {
            int d = wid * 32 + i * 8 + vrow_off;
            gl_lds16(Vbase + (long)d * 2048 + kt + vg * 8,
                     &Vs[buf][(wid * 32 + i * 8) * 64 + lane * 8]);
        }
    };

    // Q B-frags (resident; once per block, gather is amortized)
    bf16x8 qf[2][4];
#pragma unroll
    for (int qb = 0; qb < 2; qb++) {
        const u16* p = qkv + (qbase + qb * 16 + n16) * 4096 + h * 128;
#pragma unroll
        for (int c = 0; c < 4; c++) qf[qb][c] = *(const bf16x8*)(p + c * 32 + q4 * 8);
    }

    f32x4 o[2][8];
#pragma unroll
    for (int i = 0; i < 2; i++)
#pragma unroll
        for (int j = 0; j < 8; j++) o[i][j] = (f32x4){0.f, 0.f, 0.f, 0.f};
    f32x4 l_acc[2] = {(f32x4){0.f, 0.f, 0.f, 0.f}, (f32x4){0.f, 0.f, 0.f, 0.f}};

    bf16x8 ones;
#pragma unroll
    for (int j = 0; j < 8; j++) ones[j] = (short)0x3f80;   // bf16 1.0

    const int swz = n16 & 7;              // fragment-read swizzle key

    // prologue: fill buffer 0 and drain
    stage(0, 0);
    asm volatile("s_waitcnt vmcnt(0)" ::: "memory");
    __builtin_amdgcn_s_barrier();

    int cur = 0;
    for (int kt = 0; kt < 2048; kt += 64) {
        // ---- issue next tile's staging into the other buffer (async) ----
        if (kt + 64 < 2048) stage(cur ^ 1, kt + 64);

        const u16* KsC = Ks[cur];
        const u16* VsC = Vs[cur];

        // ---- S^T = K Q^T from LDS (rows are token-permuted) ----
        f32x4 s[2][4];
#pragma unroll
        for (int qb = 0; qb < 2; qb++)
#pragma unroll
            for (int kb = 0; kb < 4; kb++) s[qb][kb] = (f32x4){0.f, 0.f, 0.f, 0.f};
#pragma unroll
        for (int c = 0; c < 4; c++) {
            bf16x8 kf[4];
#pragma unroll
            for (int kb = 0; kb < 4; kb++) {
                int slot = (c * 4 + q4) ^ swz;
                kf[kb] = *(const bf16x8*)&KsC[(kb * 16 + n16) * 128 + slot * 8];
            }
            __builtin_amdgcn_s_setprio(1);
#pragma unroll
            for (int qb = 0; qb < 2; qb++)
#pragma unroll
                for (int kb = 0; kb < 4; kb++)
                    s[qb][kb] = mfma_bf16(kf[kb], qf[qb][c], s[qb][kb]);
            __builtin_amdgcn_s_setprio(0);
        }

        // ---- raw exp2 (single v_exp_f32 each); pack P in registers.
        //      s[qb][kb][r] = score of token kc*32 + q4*8 + (kb&1)*4 + r
        //      (kc = kb>>1) -- exactly the PV A-fragment slot order.
        u32 pw[2][8];
#pragma unroll
        for (int qb = 0; qb < 2; qb++)
#pragma unroll
            for (int kb = 0; kb < 4; kb++) {
                float p0 = fexp2(s[qb][kb][0]);
                float p1 = fexp2(s[qb][kb][1]);
                float p2 = fexp2(s[qb][kb][2]);
                float p3 = fexp2(s[qb][kb][3]);
                pw[qb][kb * 2]     = packtrunc(p0, p1);
                pw[qb][kb * 2 + 1] = packtrunc(p2, p3);
            }

        // ---- PV + l: A = P (registers), B = V^T-frag / ones const ----
#pragma unroll
        for (int kc = 0; kc < 2; kc++) {
            bf16x8 vf[8];
#pragma unroll
            for (int nbh = 0; nbh < 8; nbh++) {
                int slot = (kc * 4 + q4) ^ swz;
                vf[nbh] = *(const bf16x8*)&VsC[(nbh * 16 + n16) * 64 + slot * 8];
            }
            __builtin_amdgcn_s_setprio(1);
#pragma unroll
            for (int qb = 0; qb < 2; qb++) {
                union { u32 w[4]; bf16x8 v; } pu;
                pu.w[0] = pw[qb][kc * 4];
                pu.w[1] = pw[qb][kc * 4 + 1];
                pu.w[2] = pw[qb][kc * 4 + 2];
                pu.w[3] = pw[qb][kc * 4 + 3];
                l_acc[qb] = mfma_bf16(pu.v, ones, l_acc[qb]);
#pragma unroll
                for (int nbh = 0; nbh < 8; nbh++)
                    o[qb][nbh] = mfma_bf16(pu.v, vf[nbh], o[qb][nbh]);
            }
            __builtin_amdgcn_s_setprio(0);
        }

        // ---- next buffer landed + all waves done reading cur ----
        asm volatile("s_waitcnt vmcnt(0)" ::: "memory");
        __builtin_amdgcn_s_barrier();
        cur ^= 1;
    }

    // ---- epilogue: O /= l (same-lane, same-reg layout), write bf16 ----
#pragma unroll
    for (int qb = 0; qb < 2; qb++) {
        float linv[4];
#pragma unroll
        for (int r = 0; r < 4; r++) linv[r] = 1.0f / l_acc[qb][r];
#pragma unroll
        for (int r = 0; r < 4; r++) {
            u16* op = attn + (qbase + qb * 16 + q4 * 4 + r) * 2048 + h * 128 + n16;
#pragma unroll
            for (int nbh = 0; nbh < 8; nbh++)
                op[nbh * 16] = f2bf(o[qb][nbh][r] * linv[r]);
        }
    }
}

// ---------------------------------------------------------------------------
// ws layout (bytes), total 125.8 MB:
//   Bt_qkv / Vt  @ 0          16,777,216   (Vt overwrites Bt_qkv after gemm_qkv)
//   Bt_o         @ 16777216    8,388,608
//   xb / attn    @ 25165824   33,554,432   (attn overwrites xb after gemm_qkv)
//   qkv          @ 58720256   67,108,864
// ---------------------------------------------------------------------------
extern "C" void kernel_launch(void* const* d_in, const int* in_sizes, int n_in,
                              void* d_out, int out_size, void* d_ws, size_t ws_size,
                              hipStream_t stream) {
    const float* x    = (const float*)d_in[0];
    const float* cosT = (const float*)d_in[1];
    const float* sinT = (const float*)d_in[2];
    const float* Wq   = (const float*)d_in[3];
    const float* Wk   = (const float*)d_in[4];
    const float* Wv   = (const float*)d_in[5];
    const float* Wo   = (const float*)d_in[6];
    const float* qg   = (const float*)d_in[7];
    const float* kg   = (const float*)d_in[8];
    float* out = (float*)d_out;

    char* ws = (char*)d_ws;
    u16* Bt_qkv = (u16*)(ws);
    u16* Vt     = (u16*)(ws);              // reuses Bt_qkv after gemm_qkv
    u16* Bt_o   = (u16*)(ws + 16777216);
    u16* xb     = (u16*)(ws + 25165824);
    u16* attn   = (u16*)(ws + 25165824);   // reuses xb after gemm_qkv
    u16* qkv    = (u16*)(ws + 58720256);

    transpose_f2b<<<dim3(64, 64), 256, 0, stream>>>(Wq, Bt_qkv, 2048, 2048);
    transpose_f2b<<<dim3(32, 64), 256, 0, stream>>>(Wk, Bt_qkv + (size_t)2048 * 2048, 2048, 1024);
    transpose_f2b<<<dim3(32, 64), 256, 0, stream>>>(Wv, Bt_qkv + (size_t)3072 * 2048, 2048, 1024);
    transpose_f2b<<<dim3(64, 64), 256, 0, stream>>>(Wo, Bt_o, 2048, 2048);
    cast_f2b<<<dim3(8192), 256, 0, stream>>>(x, xb);

    gemm_bt_256<false><<<dim3(512), 512, 0, stream>>>(xb, Bt_qkv, qkv, 8192, 4096, 2048);

    transpose_v<<<dim3(32, 256), 256, 0, stream>>>(qkv, Vt);
    rmsnorm_rope<<<dim3(49152), 256, 0, stream>>>(qkv, cosT, sinT, qg, kg);

    flash_attn<<<dim3(16, 64), 256, 0, stream>>>(qkv, Vt, attn);

    gemm_bt_256<true><<<dim3(256), 512, 0, stream>>>(attn, Bt_o, out, 8192, 2048, 2048);
}